// Round 1
// baseline (634.536 us; speedup 1.0000x reference)
//
#include <hip/hip_runtime.h>

typedef short bx8 __attribute__((ext_vector_type(8)));
typedef unsigned short ux4 __attribute__((ext_vector_type(4)));
typedef float fx4 __attribute__((ext_vector_type(4)));

#define INV 0.08838834764831843f
#define LP 136           // padded LDS row length in bf16 elems (128 + 8)
#define TR 32            // rows per tile
#define NROWS 200000
#define NT (NROWS / TR)  // 6250 tiles
#define NTHREADS 640     // 10 waves
#define NBLOCKS 256

__device__ __forceinline__ unsigned short f2bf(float f) {
  unsigned u = __builtin_bit_cast(unsigned, f);
  u += 0x7FFFu + ((u >> 16) & 1u);   // RNE
  return (unsigned short)(u >> 16);
}
__device__ __forceinline__ float bf2f(unsigned short h) {
  unsigned u = ((unsigned)h) << 16;
  return __builtin_bit_cast(float, u);
}
__device__ __forceinline__ float sigm(float z) { return 1.0f / (1.0f + __expf(-z)); }

// Transposed-MFMA fused MLP.
// Layer-1: h' = W1^T x^T  (A = weight frags in VGPRs, B = staged x from LDS)
// C' layout: row(=out col j) = quad*4+r, col(=row n) = lane&15  -> b64 packed LDS writes
// Layer-2: out' = W2^T act^T, same trick; epilogue stores straight to global.
__global__ __launch_bounds__(NTHREADS) void nlr_kernel(
    const float* __restrict__ x, const float* __restrict__ w1_s,
    const float* __restrict__ w1_v, const float* __restrict__ w2_s,
    const float* __restrict__ w2_v, float* __restrict__ out) {
  // sS: staged s (bf16) [TR][LP]; aliased as actS in the gating phase.
  // vS[c]: staged v_c [TR][LP]; aliased as gvS[c] after layer-1 reads complete.
  // gS: gates (bf16) [TR][LP].
  __shared__ short lds[5 * TR * LP];     // 43520 B
  short* sS = lds;
  short* vS0 = lds + TR * LP;
  short* gS = lds + 4 * TR * LP;

  const int tid = threadIdx.x;
  const int w = tid >> 6;
  const int lane = tid & 63;
  const int quad = lane >> 4;
  const int c16 = lane & 15;
  const int mrow0 = quad * 8;

  // ---- build weight A-fragments (once) ----
  // A[j = lane&15][k = quad*8 + jj]; our A = W^T so element = W[kcontr][jcol]
  bx8 Wf[4][4];  // [jjb][kb]
  if (w < 4) {   // s-waves: h_s cols [w*64, w*64+64)
#pragma unroll
    for (int jjb = 0; jjb < 4; ++jjb) {
      const int col = (w * 4 + jjb) * 16 + c16;
#pragma unroll
      for (int kb = 0; kb < 4; ++kb) {
        bx8 f;
#pragma unroll
        for (int jj = 0; jj < 8; ++jj)
          f[jj] = (short)f2bf(w1_s[(kb * 32 + mrow0 + jj) * 256 + col]);
        Wf[jjb][kb] = f;
      }
    }
  } else {       // v-waves: c = (w-4)>>1, half = (w-4)&1 -> h_v cols [half*64, +64)
    const int half = (w - 4) & 1;
#pragma unroll
    for (int jjb = 0; jjb < 4; ++jjb) {
      const int col = (half * 4 + jjb) * 16 + c16;
#pragma unroll
      for (int kb = 0; kb < 4; ++kb) {
        bx8 f;
#pragma unroll
        for (int jj = 0; jj < 8; ++jj)
          f[jj] = (short)f2bf(w1_v[(kb * 32 + mrow0 + jj) * 128 + col]);
        Wf[jjb][kb] = f;
      }
    }
  }
  bx8 W2f[4];    // layer-2 weights (waves 0..7 use; g = w&3, 0 -> w2_s else w2_v)
  {
    const float* w2 = ((w & 3) == 0) ? w2_s : w2_v;
#pragma unroll
    for (int kb = 0; kb < 4; ++kb) {
      bx8 f;
#pragma unroll
      for (int jj = 0; jj < 8; ++jj)
        f[jj] = (short)f2bf(w2[(kb * 32 + mrow0 + jj) * 16 + c16]);
      W2f[kb] = f;
    }
  }

  for (int tile = blockIdx.x; tile < NT; tile += gridDim.x) {
    // ---- stage x tile -> LDS bf16, deinterleaving v into per-c arrays ----
    const float* xb = x + (size_t)tile * (TR * 512);
    for (int t = tid; t < 2048; t += NTHREADS) {
      const int n = (t & 1023) >> 5;
      const int ch = t & 31;
      if (t < 1024) {  // s region: 32 rows x 32 float4 chunks
        const fx4 f = *(const fx4*)(xb + n * 512 + ch * 4);
        ux4 p = {f2bf(f[0]), f2bf(f[1]), f2bf(f[2]), f2bf(f[3])};
        *(ux4*)(sS + n * LP + ch * 4) = p;
      } else {         // v region: 32 rows x 32 chunks of 12 floats (4 m's x 3 c's)
        const float* bp = xb + n * 512 + 128 + ch * 12;
        const fx4 a = *(const fx4*)bp;
        const fx4 b = *(const fx4*)(bp + 4);
        const fx4 c = *(const fx4*)(bp + 8);
        // i = 3m + c ; chunk covers m = ch*4 .. ch*4+3
        ux4 p0 = {f2bf(a[0]), f2bf(a[3]), f2bf(b[2]), f2bf(c[1])};
        ux4 p1 = {f2bf(a[1]), f2bf(b[0]), f2bf(b[3]), f2bf(c[2])};
        ux4 p2 = {f2bf(a[2]), f2bf(b[1]), f2bf(c[0]), f2bf(c[3])};
        *(ux4*)(vS0 + 0 * TR * LP + n * LP + ch * 4) = p0;
        *(ux4*)(vS0 + 1 * TR * LP + n * LP + ch * 4) = p1;
        *(ux4*)(vS0 + 2 * TR * LP + n * LP + ch * 4) = p2;
      }
    }
    __syncthreads();

    // ---- layer 1 (transposed): all 10 waves ----
    fx4 acc[4][2];   // [jjb][rb]
    {
      const short* src = (w < 4) ? sS : (vS0 + ((w - 4) >> 1) * TR * LP);
#pragma unroll
      for (int rb = 0; rb < 2; ++rb) {
        bx8 B[4];
        const int rbase = (rb * 16 + c16) * LP + quad * 8;
#pragma unroll
        for (int kb = 0; kb < 4; ++kb) B[kb] = *(const bx8*)(src + rbase + kb * 32);
#pragma unroll
        for (int jjb = 0; jjb < 4; ++jjb) {
          fx4 a = {0.f, 0.f, 0.f, 0.f};
#pragma unroll
          for (int kb = 0; kb < 4; ++kb)
            a = __builtin_amdgcn_mfma_f32_16x16x32_bf16(Wf[jjb][kb], B[kb], a, 0, 0, 0);
          acc[jjb][rb] = a;
        }
      }
    }
    // gate columns (h_s cols 128..255 live on waves 2,3): sigmoid -> gS now
    if (w >= 2 && w < 4) {
#pragma unroll
      for (int rb = 0; rb < 2; ++rb)
#pragma unroll
        for (int jjb = 0; jjb < 4; ++jjb) {
          const int jb = w * 4 + jjb;  // 8..15
          ux4 p;
#pragma unroll
          for (int r = 0; r < 4; ++r) p[r] = f2bf(sigm(acc[jjb][rb][r] * INV));
          *(ux4*)(gS + (rb * 16 + c16) * LP + (jb - 8) * 16 + quad * 4) = p;
        }
    }
    __syncthreads();

    // ---- activation / gating (sS,vS buffers are dead -> reuse as actS,gvS) ----
    if (w < 2) {       // silu(h_s[:, :128]) -> actS (aliases sS)
#pragma unroll
      for (int rb = 0; rb < 2; ++rb)
#pragma unroll
        for (int jjb = 0; jjb < 4; ++jjb) {
          const int jb = w * 4 + jjb;  // 0..7
          ux4 p;
#pragma unroll
          for (int r = 0; r < 4; ++r) {
            const float h = acc[jjb][rb][r] * INV;
            p[r] = f2bf(h * sigm(h));
          }
          *(ux4*)(sS + (rb * 16 + c16) * LP + jb * 16 + quad * 4) = p;
        }
    } else if (w >= 4) {  // gated_v = h_v * gates -> gvS (aliases vS[c])
      const int vc = (w - 4) >> 1, half = (w - 4) & 1;
      short* gv = vS0 + vc * TR * LP;
#pragma unroll
      for (int rb = 0; rb < 2; ++rb)
#pragma unroll
        for (int jjb = 0; jjb < 4; ++jjb) {
          const int jb = half * 4 + jjb;  // 0..7 (k-block)
          const ux4 g = *(const ux4*)(gS + (rb * 16 + c16) * LP + jb * 16 + quad * 4);
          ux4 p;
#pragma unroll
          for (int r = 0; r < 4; ++r)
            p[r] = f2bf(acc[jjb][rb][r] * INV * bf2f(g[r]));
          *(ux4*)(gv + (rb * 16 + c16) * LP + jb * 16 + quad * 4) = p;
        }
    }
    __syncthreads();

    // ---- layer 2 (transposed): waves 0..7, task = (g = w&3, rb = w>>2) ----
    if (w < 8) {
      const int g = w & 3, rb = w >> 2;
      const short* src = (g == 0) ? sS : (vS0 + (g - 1) * TR * LP);
      fx4 a = {0.f, 0.f, 0.f, 0.f};
      const int rbase = (rb * 16 + c16) * LP + quad * 8;
#pragma unroll
      for (int kb = 0; kb < 4; ++kb) {
        const bx8 B = *(const bx8*)(src + rbase + kb * 32);
        a = __builtin_amdgcn_mfma_f32_16x16x32_bf16(W2f[kb], B, a, 0, 0, 0);
      }
      const size_t n = (size_t)tile * TR + rb * 16 + c16;
      if (g == 0) {
        // out[n][j], j = quad*4 + r : contiguous -> float4 store
        fx4 o = {a[0] * INV, a[1] * INV, a[2] * INV, a[3] * INV};
        *(fx4*)(out + n * 64 + quad * 4) = o;
      } else {
        // out_v reshaped: col = 16 + 3*j + c
        const int c = g - 1;
#pragma unroll
        for (int r = 0; r < 4; ++r)
          out[n * 64 + 16 + 3 * (quad * 4 + r) + c] = a[r] * INV;
      }
    }
    __syncthreads();  // protect actS/gvS (read above) from next tile's staging
  }
}

extern "C" void kernel_launch(void* const* d_in, const int* in_sizes, int n_in,
                              void* d_out, int out_size, void* d_ws, size_t ws_size,
                              hipStream_t stream) {
  const float* x    = (const float*)d_in[0];
  const float* w1_s = (const float*)d_in[1];
  const float* w1_v = (const float*)d_in[2];
  const float* w2_s = (const float*)d_in[3];
  const float* w2_v = (const float*)d_in[4];
  nlr_kernel<<<NBLOCKS, NTHREADS, 0, stream>>>(x, w1_s, w1_v, w2_s, w2_v, (float*)d_out);
}

// Round 2
// 583.741 us; speedup vs baseline: 1.0870x; 1.0870x over previous
//
#include <hip/hip_runtime.h>

typedef short bx8 __attribute__((ext_vector_type(8)));
typedef unsigned short ux4 __attribute__((ext_vector_type(4)));
typedef float fx4 __attribute__((ext_vector_type(4)));

#define INV 0.08838834764831843f
#define LP 136           // padded LDS row length in bf16 elems (mult of 8 for b128 alignment)
#define TR 16            // rows per tile
#define NROWS 200000
#define NT (NROWS / TR)  // 12500 tiles
#define NTHREADS 640     // 10 waves
#define NBLOCKS 256

__device__ __forceinline__ unsigned short f2bf(float f) {
  unsigned u = __builtin_bit_cast(unsigned, f);
  u += 0x7FFFu + ((u >> 16) & 1u);   // RNE
  return (unsigned short)(u >> 16);
}
__device__ __forceinline__ float bf2f(unsigned short h) {
  unsigned u = ((unsigned)h) << 16;
  return __builtin_bit_cast(float, u);
}
__device__ __forceinline__ float sigm(float z) { return 1.0f / (1.0f + __expf(-z)); }

// Transposed-MFMA fused MLP, software-pipelined:
//   per tile: [cvt regs->X] B1 [prefetch next tile->regs; L1; gates->GS] B2
//             [act/gv->ACT] B3 [L2 from ACT; store]   (3 barriers, no aliasing)
__global__ __launch_bounds__(NTHREADS) void nlr_kernel(
    const float* __restrict__ x, const float* __restrict__ w1_s,
    const float* __restrict__ w1_v, const float* __restrict__ w2_s,
    const float* __restrict__ w2_v, float* __restrict__ out) {
  __shared__ short lds[9 * TR * LP];   // X(4 grp) + ACT(4 grp) + GS = 39168 B
  short* X = lds;                      // groups: s, v0, v1, v2  each [TR][LP]
  short* ACT = lds + 4 * TR * LP;      // groups: act_s, gv0, gv1, gv2
  short* GS = lds + 8 * TR * LP;       // gates [TR][128]

  const int tid = threadIdx.x;
  const int w = tid >> 6;
  const int lane = tid & 63;
  const int quad = lane >> 4;
  const int c16 = lane & 15;
  const int mrow0 = quad * 8;

  // ---- staging role constants ----
  // 1024 16B/48B chunks per tile: t<512 -> s chunk, t>=512 -> v chunk.
  // thread handles chunk tid (if <1024... tid<512: s) and chunk tid+640 (v).
  const bool hasS = tid < 512;
  const bool hasV = (tid < 384) || (tid >= 512);
  const int sn = tid >> 5, sch = tid & 31;                  // s: row, float4-chunk
  const int vu = (tid < 384) ? (tid + 128) : (tid - 512);   // v chunk id
  const int vn = vu >> 5, vch = vu & 31;                    // v: row, 12-float chunk

  // ---- build weight A-fragments (once) ----
  bx8 Wf[4][4];  // [jjb][kb]
  if (w < 4) {   // s-waves: h_s cols [w*64, w*64+64)
#pragma unroll
    for (int jjb = 0; jjb < 4; ++jjb) {
      const int col = (w * 4 + jjb) * 16 + c16;
#pragma unroll
      for (int kb = 0; kb < 4; ++kb) {
        bx8 f;
#pragma unroll
        for (int jj = 0; jj < 8; ++jj)
          f[jj] = (short)f2bf(w1_s[(kb * 32 + mrow0 + jj) * 256 + col]);
        Wf[jjb][kb] = f;
      }
    }
  } else {       // v-waves: c = (w-4)>>1, half = (w-4)&1
    const int half = (w - 4) & 1;
#pragma unroll
    for (int jjb = 0; jjb < 4; ++jjb) {
      const int col = (half * 4 + jjb) * 16 + c16;
#pragma unroll
      for (int kb = 0; kb < 4; ++kb) {
        bx8 f;
#pragma unroll
        for (int jj = 0; jj < 8; ++jj)
          f[jj] = (short)f2bf(w1_v[(kb * 32 + mrow0 + jj) * 128 + col]);
        Wf[jjb][kb] = f;
      }
    }
  }
  bx8 W2f[4];    // layer-2 weights (wave w<4 uses group g=w; 0 -> w2_s else w2_v)
  {
    const float* w2 = (w == 0) ? w2_s : w2_v;
#pragma unroll
    for (int kb = 0; kb < 4; ++kb) {
      bx8 f;
#pragma unroll
      for (int jj = 0; jj < 8; ++jj)
        f[jj] = (short)f2bf(w2[(kb * 32 + mrow0 + jj) * 16 + c16]);
      W2f[kb] = f;
    }
  }

  // ---- prefetch registers ----
  fx4 pf_s, pf_a, pf_b, pf_c;

  int tile = blockIdx.x;
  {  // prologue load
    const float* xb = x + (size_t)tile * (TR * 512);
    if (hasS) pf_s = *(const fx4*)(xb + sn * 512 + sch * 4);
    if (hasV) {
      const float* bp = xb + vn * 512 + 128 + vch * 12;
      pf_a = *(const fx4*)bp; pf_b = *(const fx4*)(bp + 4); pf_c = *(const fx4*)(bp + 8);
    }
  }

  while (tile < NT) {
    // ---- phase A: convert prefetched regs -> X staging ----
    if (hasS) {
      ux4 p = {f2bf(pf_s[0]), f2bf(pf_s[1]), f2bf(pf_s[2]), f2bf(pf_s[3])};
      *(ux4*)(X + sn * LP + sch * 4) = p;
    }
    if (hasV) {
      // i = 3m + c ; chunk covers m = vch*4 .. vch*4+3
      ux4 p0 = {f2bf(pf_a[0]), f2bf(pf_a[3]), f2bf(pf_b[2]), f2bf(pf_c[1])};
      ux4 p1 = {f2bf(pf_a[1]), f2bf(pf_b[0]), f2bf(pf_b[3]), f2bf(pf_c[2])};
      ux4 p2 = {f2bf(pf_a[2]), f2bf(pf_b[1]), f2bf(pf_c[0]), f2bf(pf_c[3])};
      *(ux4*)(X + 1 * TR * LP + vn * LP + vch * 4) = p0;
      *(ux4*)(X + 2 * TR * LP + vn * LP + vch * 4) = p1;
      *(ux4*)(X + 3 * TR * LP + vn * LP + vch * 4) = p2;
    }
    const int nxt = tile + NBLOCKS;
    __syncthreads();  // B1: X visible; prior-iter ACT reads done

    // ---- issue next tile's global loads (hide behind L1/act compute) ----
    if (nxt < NT) {
      const float* xb = x + (size_t)nxt * (TR * 512);
      if (hasS) pf_s = *(const fx4*)(xb + sn * 512 + sch * 4);
      if (hasV) {
        const float* bp = xb + vn * 512 + 128 + vch * 12;
        pf_a = *(const fx4*)bp; pf_b = *(const fx4*)(bp + 4); pf_c = *(const fx4*)(bp + 8);
      }
    }

    // ---- phase B: layer 1 (all 10 waves), gates -> GS (waves 2,3) ----
    fx4 acc[4];
    {
      const short* src = (w < 4) ? X : (X + (1 + ((w - 4) >> 1)) * TR * LP);
      bx8 B[4];
      const int rbase = c16 * LP + mrow0;
#pragma unroll
      for (int kb = 0; kb < 4; ++kb) B[kb] = *(const bx8*)(src + rbase + kb * 32);
#pragma unroll
      for (int jjb = 0; jjb < 4; ++jjb) {
        fx4 a = {0.f, 0.f, 0.f, 0.f};
#pragma unroll
        for (int kb = 0; kb < 4; ++kb)
          a = __builtin_amdgcn_mfma_f32_16x16x32_bf16(Wf[jjb][kb], B[kb], a, 0, 0, 0);
        acc[jjb] = a;
      }
    }
    if (w == 2 || w == 3) {  // gate cols 128..255 -> sigmoid -> GS
#pragma unroll
      for (int jjb = 0; jjb < 4; ++jjb) {
        const int jb = w * 4 + jjb;  // 8..15
        ux4 p;
#pragma unroll
        for (int r = 0; r < 4; ++r) p[r] = f2bf(sigm(acc[jjb][r] * INV));
        *(ux4*)(GS + c16 * LP + (jb - 8) * 16 + quad * 4) = p;
      }
    }
    __syncthreads();  // B2: gates visible; X reads done

    // ---- phase C: act (waves 0,1) / gated_v (waves 4-9) -> ACT ----
    if (w < 2) {
#pragma unroll
      for (int jjb = 0; jjb < 4; ++jjb) {
        const int jb = w * 4 + jjb;  // 0..7
        ux4 p;
#pragma unroll
        for (int r = 0; r < 4; ++r) {
          const float h = acc[jjb][r] * INV;
          p[r] = f2bf(h * sigm(h));
        }
        *(ux4*)(ACT + c16 * LP + jb * 16 + quad * 4) = p;
      }
    } else if (w >= 4) {
      const int vc = (w - 4) >> 1, half = (w - 4) & 1;
      short* gv = ACT + (1 + vc) * TR * LP;
#pragma unroll
      for (int jjb = 0; jjb < 4; ++jjb) {
        const int jb = half * 4 + jjb;  // 0..7 (k-block)
        const ux4 g = *(const ux4*)(GS + c16 * LP + jb * 16 + quad * 4);
        ux4 p;
#pragma unroll
        for (int r = 0; r < 4; ++r)
          p[r] = f2bf(acc[jjb][r] * INV * bf2f(g[r]));
        *(ux4*)(gv + c16 * LP + jb * 16 + quad * 4) = p;
      }
    }
    __syncthreads();  // B3: ACT visible

    // ---- phase D: layer 2 (waves 0-3 only; g = w), store to global ----
    if (w < 4) {
      const short* src = ACT + w * TR * LP;
      fx4 a = {0.f, 0.f, 0.f, 0.f};
      const int rbase = c16 * LP + mrow0;
#pragma unroll
      for (int kb = 0; kb < 4; ++kb) {
        const bx8 B = *(const bx8*)(src + rbase + kb * 32);
        a = __builtin_amdgcn_mfma_f32_16x16x32_bf16(W2f[kb], B, a, 0, 0, 0);
      }
      const size_t n = (size_t)tile * TR + c16;
      if (w == 0) {
        fx4 o = {a[0] * INV, a[1] * INV, a[2] * INV, a[3] * INV};
        *(fx4*)(out + n * 64 + quad * 4) = o;
      } else {
        const int c = w - 1;
#pragma unroll
        for (int r = 0; r < 4; ++r)
          out[n * 64 + 16 + 3 * (quad * 4 + r) + c] = a[r] * INV;
      }
    }
    // no barrier here: next phase A writes X, disjoint from ACT/GS reads above;
    // B1 of the next iteration provides the cross-phase sync.
    tile = nxt;
  }
}

extern "C" void kernel_launch(void* const* d_in, const int* in_sizes, int n_in,
                              void* d_out, int out_size, void* d_ws, size_t ws_size,
                              hipStream_t stream) {
  const float* x    = (const float*)d_in[0];
  const float* w1_s = (const float*)d_in[1];
  const float* w1_v = (const float*)d_in[2];
  const float* w2_s = (const float*)d_in[3];
  const float* w2_v = (const float*)d_in[4];
  nlr_kernel<<<NBLOCKS, NTHREADS, 0, stream>>>(x, w1_s, w1_v, w2_s, w2_v, (float*)d_out);
}